// Round 5
// baseline (38499.295 us; speedup 1.0000x reference)
//
#include <hip/hip_runtime.h>
#include <hip/hip_bf16.h>

// R5: GOLDEN SLOW PATH. Entire MHA in scalar fp32 VALU — no MFMA, no LDS
// tiling, no layout cleverness. Purpose: validate semantics + harness
// interface (dtype worlds, buffer sizes, scratch plan) in isolation.
// R4 decode: NaN was the d_ws-size assumption (r2 vs r4 delta); remaining
// 0.778 error = shared-path bug that survived inspection -> instrument.
//  - ws_size finally CHECKED host-side: fp32 scratch in d_ws if >=64MiB,
//    else bf16 scratch in recycled buffers (r4 plan).
//  - dtype detect per block (bf16 vs fp32 inputs), both worlds supported.

#define B_ 2
#define S_ 2048
#define D_ 1024
#define H_ 16
#define HD_ 64

typedef unsigned short u16;
typedef unsigned int u32;
typedef u16 __attribute__((may_alias)) u16_ma;
typedef float __attribute__((may_alias)) f32_ma;
typedef u32 __attribute__((may_alias)) u32_ma;
typedef u32 v4u __attribute__((ext_vector_type(4)));
typedef v4u __attribute__((may_alias)) v4u_ma;

__device__ __forceinline__ float bf2f(u16 u) {
  u32 x = ((u32)u) << 16;
  return __builtin_bit_cast(float, x);
}
__device__ __forceinline__ u16 f2bf(float f) {
  __hip_bfloat16 h = __float2bfloat16(f);
  return __builtin_bit_cast(u16, h);
}

// Input dtype detect: scan first 2048 u16 of a weight buffer for bf16
// exponent field >= 0xF0 (impossible for bf16 weights ~N(0,4e-4); ~1/16
// per u16 for fp32 low-mantissa halves). Deterministic across waves/blocks
// (all scan the same 2048 u16).
__device__ __forceinline__ bool detect_f32(const u16* Wg) {
  const int lane = threadIdx.x & 63;
  bool hit = false;
#pragma unroll
  for (int i = 0; i < 4; ++i) {
    v4u_ma u = *(const v4u_ma*)(Wg + lane * 32 + i * 8);
#pragma unroll
    for (int j = 0; j < 4; ++j) {
      u32 w = u[j];
      hit |= (((w >> 7) & 0xFFu) >= 0xF0u) || (((w >> 23) & 0xFFu) >= 0xF0u);
    }
  }
  return __any(hit);
}

// C[m][n] = sum_k A[m][k] * W[n][k]  (torch Linear), scalar fp32.
// A_SCR: A is internal scratch (dtype = SCR_F32) else original input (dtype
// per detect). OUT_FINAL: C is d_out (dtype per detect) else scratch.
template <bool A_SCR, bool SCR_F32, bool OUT_FINAL>
__global__ __launch_bounds__(256) void proj_slow(
    const void* __restrict__ Ag, const u16* __restrict__ Wg,
    void* __restrict__ Cg) {
  const bool det = detect_f32(Wg);
  const bool a_f32 = A_SCR ? SCR_F32 : det;
  const int m = blockIdx.x;                        // 0..4095
  const int n = blockIdx.y * 256 + threadIdx.x;    // 0..1023
  const size_t arow = (size_t)m * D_;
  const size_t wrow = (size_t)n * D_;
  float acc = 0.f;
  for (int k = 0; k < D_; ++k) {
    float a = a_f32 ? ((const f32_ma*)Ag)[arow + k]
                    : bf2f(((const u16_ma*)Ag)[arow + k]);
    float w = det ? ((const f32_ma*)Wg)[wrow + k]
                  : bf2f(((const u16_ma*)Wg)[wrow + k]);
    acc += a * w;
  }
  const size_t ci = (size_t)m * D_ + n;
  const bool c_f32 = OUT_FINAL ? det : SCR_F32;
  if (c_f32)
    ((f32_ma*)Cg)[ci] = acc;
  else
    ((u16_ma*)Cg)[ci] = f2bf(acc);
}

// Attention, scalar fp32, exact online softmax. One thread = one (b,h,q).
// All Q/K/V/C are scratch buffers of dtype SCR_F32.
template <bool SCR_F32>
__global__ __launch_bounds__(256) void attn_slow(
    const void* __restrict__ Qg, const void* __restrict__ Kg,
    const void* __restrict__ Vg, void* __restrict__ Cg) {
  const int tid = threadIdx.x;
  const int qblk = blockIdx.x & 7;
  const int h = (blockIdx.x >> 3) & 15;
  const int b = blockIdx.x >> 7;
  const int q = qblk * 256 + tid;
  const size_t base = (size_t)b * S_ * D_;
  const int hoff = h * HD_;

  float qv[64];
  {
    const size_t qrow = base + (size_t)q * D_ + hoff;
    for (int d = 0; d < 64; ++d)
      qv[d] = SCR_F32 ? ((const f32_ma*)Qg)[qrow + d]
                      : bf2f(((const u16_ma*)Qg)[qrow + d]);
  }

  float o[64];
  for (int d = 0; d < 64; ++d) o[d] = 0.f;
  float m = -1e30f, l = 0.f;

  for (int key = 0; key < S_; ++key) {
    const size_t krow = base + (size_t)key * D_ + hoff;
    float s = 0.f;
    for (int d = 0; d < 64; ++d) {
      float kx = SCR_F32 ? ((const f32_ma*)Kg)[krow + d]
                         : bf2f(((const u16_ma*)Kg)[krow + d]);
      s += qv[d] * kx;
    }
    s *= 0.125f;  // 1/sqrt(64)
    float mn = fmaxf(m, s);
    float al = expf(m - mn);
    float pe = expf(s - mn);
    m = mn;
    l = l * al + pe;
    for (int d = 0; d < 64; ++d) {
      float vx = SCR_F32 ? ((const f32_ma*)Vg)[krow + d]
                         : bf2f(((const u16_ma*)Vg)[krow + d]);
      o[d] = o[d] * al + pe * vx;
    }
  }

  const float il = 1.f / l;  // l >= 1
  const size_t crow = base + (size_t)q * D_ + hoff;
  for (int d = 0; d < 64; ++d) {
    if (SCR_F32)
      ((f32_ma*)Cg)[crow + d] = o[d] * il;
    else
      ((u16_ma*)Cg)[crow + d] = f2bf(o[d] * il);
  }
}

extern "C" void kernel_launch(void* const* d_in, const int* in_sizes, int n_in,
                              void* d_out, int out_size, void* d_ws,
                              size_t ws_size, hipStream_t stream) {
  const u16* q_in = (const u16*)d_in[0];
  const u16* k_in = (const u16*)d_in[1];
  const u16* v_in = (const u16*)d_in[2];
  const u16* Wq = (const u16*)d_in[3];
  const u16* Wk = (const u16*)d_in[4];
  const u16* Wv = (const u16*)d_in[5];
  const u16* Wo = (const u16*)d_in[6];

  const size_t NE = (size_t)B_ * S_ * D_;  // 4194304 elements per buffer
  dim3 gproj(B_ * S_, D_ / 256);           // (4096, 4)
  dim3 blk(256);
  dim3 gattn(B_ * H_ * (S_ / 256));        // 256

  if (ws_size >= 4 * NE * sizeof(float)) {
    // fp32 scratch in d_ws (size VERIFIED host-side this time).
    float* Qp = (float*)d_ws;
    float* Kp = Qp + NE;
    float* Vp = Kp + NE;
    float* Xp = Vp + NE;
    proj_slow<false, true, false><<<gproj, blk, 0, stream>>>(q_in, Wq, Qp);
    proj_slow<false, true, false><<<gproj, blk, 0, stream>>>(k_in, Wk, Kp);
    proj_slow<false, true, false><<<gproj, blk, 0, stream>>>(v_in, Wv, Vp);
    attn_slow<true><<<gattn, blk, 0, stream>>>(Qp, Kp, Vp, Xp);
    proj_slow<true, true, true><<<gproj, blk, 0, stream>>>(Xp, Wo, d_out);
  } else {
    // bf16 scratch in recycled buffers (each >= 8 MB in both dtype worlds;
    // every producer/consumer pair disjoint, stream-ordered; harness
    // restores d_in from pristine copies before every launch).
    u16* Qp = (u16*)d_out;
    u16* Kp = (u16*)d_in[0];
    u16* Vp = (u16*)d_in[1];
    u16* Xp = (u16*)d_in[2];
    proj_slow<false, false, false><<<gproj, blk, 0, stream>>>(q_in, Wq, Qp);
    proj_slow<false, false, false><<<gproj, blk, 0, stream>>>(k_in, Wk, Kp);
    proj_slow<false, false, false><<<gproj, blk, 0, stream>>>(v_in, Wv, Vp);
    attn_slow<false><<<gattn, blk, 0, stream>>>(Qp, Kp, Vp, Xp);
    proj_slow<true, false, true><<<gproj, blk, 0, stream>>>(Xp, Wo, d_out);
  }
}